// Round 1
// baseline (925.925 us; speedup 1.0000x reference)
//
#include <hip/hip_runtime.h>

#define NNODES 149120
#define NEDGES 2385920
#define NB 64
#define NPMTS 2330
#define HEADK (NPMTS * 3)   // 6990
#define BN_EPS 1e-5f

// ---------------- degree / normalization ----------------

__global__ void k_deg(const int* __restrict__ dst, int* __restrict__ deg) {
    int i = blockIdx.x * blockDim.x + threadIdx.x;
    if (i < NEDGES) atomicAdd(&deg[dst[i]], 1);
}

__global__ void k_dinv(const int* __restrict__ deg, float* __restrict__ dinv) {
    int i = blockIdx.x * blockDim.x + threadIdx.x;
    if (i < NNODES) dinv[i] = rsqrtf((float)(deg[i] + 1));  // +1 self-loop
}

// ---------------- h = x @ W, fused self-loop init: out = h * dinv^2 ----------------

template<int CIN, int COUT>
__global__ void k_matmul_selfloop(const float* __restrict__ x, const float* __restrict__ W,
                                  const float* __restrict__ dinv,
                                  float* __restrict__ h, float* __restrict__ out) {
    long long t = (long long)blockIdx.x * blockDim.x + threadIdx.x;
    if (t >= (long long)NNODES * COUT) return;
    int n = (int)(t / COUT);
    int c = (int)(t % COUT);
    float acc = 0.f;
#pragma unroll
    for (int k = 0; k < CIN; ++k) acc += x[n * CIN + k] * W[k * COUT + c];
    h[t] = acc;
    float di = dinv[n];
    out[t] = acc * di * di;
}

// ---------------- edge scatter: out[dst] += h[src] * dinv[src]*dinv[dst] ----------------

template<int C>
__global__ void k_scatter(const int* __restrict__ src, const int* __restrict__ dst,
                          const float* __restrict__ dinv,
                          const float* __restrict__ h, float* __restrict__ out) {
    long long t = (long long)blockIdx.x * blockDim.x + threadIdx.x;
    if constexpr (C == 3) {
        if (t >= NEDGES) return;
        int s = src[t], d = dst[t];
        float nm = dinv[s] * dinv[d];
#pragma unroll
        for (int c = 0; c < 3; ++c)
            atomicAdd(&out[d * 3 + c], h[s * 3 + c] * nm);
    } else {
        if (t >= (long long)NEDGES * C) return;
        int e = (int)(t / C);
        int c = (int)(t % C);
        int s = src[e], d = dst[e];
        float nm = dinv[s] * dinv[d];
        atomicAdd(&out[d * C + c], h[s * C + c] * nm);
    }
}

// ---------------- out = relu(out + b) ----------------

template<int C>
__global__ void k_bias_relu(float* __restrict__ out, const float* __restrict__ b) {
    long long t = (long long)blockIdx.x * blockDim.x + threadIdx.x;
    if (t >= (long long)NNODES * C) return;
    int c = (int)(t % C);
    float v = out[t] + b[c];
    out[t] = v > 0.f ? v : 0.f;
}

// ---------------- head: z[b][j] = h3[b,:] . Wl1[:,j] + bl1[j] ----------------

__global__ void k_head(const float* __restrict__ h3, const float* __restrict__ Wl1,
                       const float* __restrict__ bl1, float* __restrict__ z) {
    int b = blockIdx.x >> 5;
    int j = blockIdx.x & 31;
    int lane = threadIdx.x;  // blockDim = 64
    float acc = 0.f;
    for (int k = lane; k < HEADK; k += 64)
        acc += h3[b * HEADK + k] * Wl1[k * 32 + j];
#pragma unroll
    for (int off = 32; off; off >>= 1) acc += __shfl_down(acc, off);
    if (lane == 0) z[b * 32 + j] = acc + bl1[j];
}

// ---------------- BN (biased var) + ReLU + final linear ----------------

__global__ void k_bn_final(const float* __restrict__ z, const float* __restrict__ gamma,
                           const float* __restrict__ beta, const float* __restrict__ Wl2,
                           const float* __restrict__ bl2, float* __restrict__ out) {
    __shared__ float zs[NB][32];
    __shared__ float scale[32], shift[32];
    int tid = threadIdx.x;  // 256
    for (int i = tid; i < NB * 32; i += 256) zs[i >> 5][i & 31] = z[i];
    __syncthreads();
    if (tid < 32) {
        float m = 0.f, v = 0.f;
        for (int b = 0; b < NB; ++b) { float xv = zs[b][tid]; m += xv; v += xv * xv; }
        m /= (float)NB;
        v = v / (float)NB - m * m;
        float sc = gamma[tid] * rsqrtf(v + BN_EPS);
        scale[tid] = sc;
        shift[tid] = beta[tid] - m * sc;
    }
    __syncthreads();
    if (tid < NB) {
        float acc = bl2[0];
#pragma unroll
        for (int j = 0; j < 32; ++j) {
            float zv = zs[tid][j] * scale[j] + shift[j];
            zv = zv > 0.f ? zv : 0.f;
            acc += zv * Wl2[j];
        }
        out[tid] = acc;
    }
}

// ---------------- launch ----------------

extern "C" void kernel_launch(void* const* d_in, const int* in_sizes, int n_in,
                              void* d_out, int out_size, void* d_ws, size_t ws_size,
                              hipStream_t stream) {
    const float* x    = (const float*)d_in[0];
    const int*   ei   = (const int*)d_in[1];
    const float* W1   = (const float*)d_in[2];
    const float* b1   = (const float*)d_in[3];
    const float* W2   = (const float*)d_in[4];
    const float* b2   = (const float*)d_in[5];
    const float* W3   = (const float*)d_in[6];
    const float* b3   = (const float*)d_in[7];
    const float* Wl1  = (const float*)d_in[8];
    const float* bl1  = (const float*)d_in[9];
    const float* gamma= (const float*)d_in[10];
    const float* beta = (const float*)d_in[11];
    const float* Wl2  = (const float*)d_in[12];
    const float* bl2  = (const float*)d_in[13];

    const int* src = ei;            // edge_index[0]
    const int* dst = ei + NEDGES;   // edge_index[1]

    char* ws = (char*)d_ws;
    float* dinv = (float*)ws;
    int*   deg  = (int*)(ws + (size_t)NNODES * 4);
    float* bufA = (float*)(ws + (size_t)NNODES * 8);                          // h
    float* bufB = (float*)(ws + (size_t)NNODES * 8 + (size_t)NNODES * 128);   // agg ping
    float* bufC = (float*)(ws + (size_t)NNODES * 8 + (size_t)NNODES * 256);   // agg pong
    float* z    = (float*)(ws + (size_t)NNODES * 8 + (size_t)NNODES * 384);   // [64,32]

    float* outp = (float*)d_out;

    // degrees + dinv (graph is identical for all 3 layers)
    hipMemsetAsync(deg, 0, (size_t)NNODES * 4, stream);
    k_deg<<<(NEDGES + 255) / 256, 256, 0, stream>>>(dst, deg);
    k_dinv<<<(NNODES + 255) / 256, 256, 0, stream>>>(deg, dinv);

    // ---- layer 1: x[N,5] -> bufB[N,32]
    k_matmul_selfloop<5, 32><<<(int)(((long long)NNODES * 32 + 255) / 256), 256, 0, stream>>>(
        x, W1, dinv, bufA, bufB);
    k_scatter<32><<<(int)(((long long)NEDGES * 32 + 255) / 256), 256, 0, stream>>>(
        src, dst, dinv, bufA, bufB);
    k_bias_relu<32><<<(int)(((long long)NNODES * 32 + 255) / 256), 256, 0, stream>>>(bufB, b1);

    // ---- layer 2: bufB[N,32] -> bufC[N,16]
    k_matmul_selfloop<32, 16><<<(int)(((long long)NNODES * 16 + 255) / 256), 256, 0, stream>>>(
        bufB, W2, dinv, bufA, bufC);
    k_scatter<16><<<(int)(((long long)NEDGES * 16 + 255) / 256), 256, 0, stream>>>(
        src, dst, dinv, bufA, bufC);
    k_bias_relu<16><<<(int)(((long long)NNODES * 16 + 255) / 256), 256, 0, stream>>>(bufC, b2);

    // ---- layer 3: bufC[N,16] -> bufB[N,3]
    k_matmul_selfloop<16, 3><<<(int)(((long long)NNODES * 3 + 255) / 256), 256, 0, stream>>>(
        bufC, W3, dinv, bufA, bufB);
    k_scatter<3><<<(NEDGES + 255) / 256, 256, 0, stream>>>(
        src, dst, dinv, bufA, bufB);
    k_bias_relu<3><<<(int)(((long long)NNODES * 3 + 255) / 256), 256, 0, stream>>>(bufB, b3);

    // ---- head: [64,6990] @ [6990,32] + BN + ReLU + [32,1]
    k_head<<<NB * 32, 64, 0, stream>>>(bufB, Wl1, bl1, z);
    k_bn_final<<<1, 256, 0, stream>>>(z, gamma, beta, Wl2, bl2, outp);
}

// Round 2
// 583.993 us; speedup vs baseline: 1.5855x; 1.5855x over previous
//
#include <hip/hip_runtime.h>

#define NNODES 149120
#define NEDGES 2385920
#define NB 64
#define NPMTS 2330
#define HEADK (NPMTS * 3)   // 6990
#define BN_EPS 1e-5f

// ---------------- degree / normalization ----------------

__global__ void k_deg(const int* __restrict__ dst, int* __restrict__ deg) {
    int i = blockIdx.x * blockDim.x + threadIdx.x;
    if (i < NEDGES) atomicAdd(&deg[dst[i]], 1);
}

__global__ void k_dinv(const int* __restrict__ deg, float* __restrict__ dinv) {
    int i = blockIdx.x * blockDim.x + threadIdx.x;
    if (i < NNODES) dinv[i] = rsqrtf((float)(deg[i] + 1));  // +1 self-loop
}

// ---------------- layer-1 pre-scale: xs = x * dinv (per-row); agg1 init = xs ----------------

__global__ void k_pre1(const float* __restrict__ x, const float* __restrict__ dinv,
                       float* __restrict__ xs, float* __restrict__ agg1) {
    unsigned t = blockIdx.x * blockDim.x + threadIdx.x;
    if (t >= (unsigned)NNODES * 5u) return;
    unsigned n = t / 5u;
    float v = x[t] * dinv[n];
    xs[t] = v;
    agg1[t] = v;   // self-loop term (scaled space)
}

// ---------------- edge scatters: agg[dst] += srcbuf[src] (pre-scaled) ----------------

__global__ void k_scatter5(const int* __restrict__ src, const int* __restrict__ dst,
                           const float* __restrict__ h, float* __restrict__ agg) {
    unsigned t = blockIdx.x * blockDim.x + threadIdx.x;
    if (t >= (unsigned)NEDGES * 5u) return;
    unsigned e = t / 5u, c = t - e * 5u;
    int s = src[e], d = dst[e];
    atomicAdd(&agg[(unsigned)d * 5u + c], h[(unsigned)s * 5u + c]);
}

__global__ void k_scatter16(const int* __restrict__ src, const int* __restrict__ dst,
                            const float* __restrict__ h, float* __restrict__ agg) {
    unsigned t = blockIdx.x * blockDim.x + threadIdx.x;
    if (t >= (unsigned)NEDGES * 16u) return;
    unsigned e = t >> 4, c = t & 15u;
    int s = src[e], d = dst[e];
    atomicAdd(&agg[(unsigned)d * 16u + c], h[(unsigned)s * 16u + c]);
}

__global__ void k_scatter3(const int* __restrict__ src, const int* __restrict__ dst,
                           const float* __restrict__ h, float* __restrict__ agg) {
    unsigned t = blockIdx.x * blockDim.x + threadIdx.x;
    if (t >= (unsigned)NEDGES * 3u) return;
    unsigned e = t / 3u, c = t - e * 3u;
    int s = src[e], d = dst[e];
    atomicAdd(&agg[(unsigned)d * 3u + c], h[(unsigned)s * 3u + c]);
}

// ---------------- fused: h1 = relu(agg1*dinv @ W1 + b1); g2s = (h1@W2)*dinv ----------------
// writes g2s (scatter source) and agg2 init (= g2s, the self-loop term)

__global__ void k_mm12(const float* __restrict__ agg1, const float* __restrict__ dinv,
                       const float* __restrict__ W1, const float* __restrict__ b1,
                       const float* __restrict__ W2,
                       float* __restrict__ g2s, float* __restrict__ agg2) {
    __shared__ float W1s[5 * 32], W2s[32 * 16], b1s[32];
    int tid = threadIdx.x;  // 256
    if (tid < 5 * 32) W1s[tid] = W1[tid];
    if (tid < 32) b1s[tid] = b1[tid];
    for (int i = tid; i < 32 * 16; i += 256) W2s[i] = W2[i];
    __syncthreads();

    unsigned n = blockIdx.x * blockDim.x + tid;
    if (n >= NNODES) return;
    float di = dinv[n];
    float a[5];
#pragma unroll
    for (int k = 0; k < 5; ++k) a[k] = agg1[n * 5u + k] * di;

    float h[32];
#pragma unroll
    for (int j = 0; j < 32; ++j) {
        float acc = b1s[j];
#pragma unroll
        for (int k = 0; k < 5; ++k) acc += a[k] * W1s[k * 32 + j];
        h[j] = acc > 0.f ? acc : 0.f;
    }
    float g[16];
#pragma unroll
    for (int c = 0; c < 16; ++c) g[c] = 0.f;
#pragma unroll
    for (int j = 0; j < 32; ++j) {
        float hj = h[j];
#pragma unroll
        for (int c = 0; c < 16; ++c) g[c] += hj * W2s[j * 16 + c];
    }
#pragma unroll
    for (int c = 0; c < 16; ++c) {
        float v = g[c] * di;
        g2s[n * 16u + c] = v;
        agg2[n * 16u + c] = v;
    }
}

// ---------------- fused: t2 = relu(agg2*dinv + b2); g3s = (t2@W3)*dinv ----------------

__global__ void k_mm3(const float* __restrict__ agg2, const float* __restrict__ dinv,
                      const float* __restrict__ b2, const float* __restrict__ W3,
                      float* __restrict__ g3s, float* __restrict__ agg3) {
    __shared__ float W3s[16 * 3], b2s[16];
    int tid = threadIdx.x;
    if (tid < 16 * 3) W3s[tid] = W3[tid];
    if (tid < 16) b2s[tid] = b2[tid];
    __syncthreads();

    unsigned n = blockIdx.x * blockDim.x + tid;
    if (n >= NNODES) return;
    float di = dinv[n];
    float t2[16];
#pragma unroll
    for (int j = 0; j < 16; ++j) {
        float v = agg2[n * 16u + j] * di + b2s[j];
        t2[j] = v > 0.f ? v : 0.f;
    }
    float g[3] = {0.f, 0.f, 0.f};
#pragma unroll
    for (int j = 0; j < 16; ++j) {
        float tj = t2[j];
#pragma unroll
        for (int c = 0; c < 3; ++c) g[c] += tj * W3s[j * 3 + c];
    }
#pragma unroll
    for (int c = 0; c < 3; ++c) {
        float v = g[c] * di;
        g3s[n * 3u + c] = v;
        agg3[n * 3u + c] = v;
    }
}

// ---------------- finalize layer 3: h3 = relu(agg3*dinv + b3) ----------------

__global__ void k_final3(const float* __restrict__ agg3, const float* __restrict__ dinv,
                         const float* __restrict__ b3, float* __restrict__ h3) {
    unsigned t = blockIdx.x * blockDim.x + threadIdx.x;
    if (t >= (unsigned)NNODES * 3u) return;
    unsigned n = t / 3u, c = t - n * 3u;
    float v = agg3[t] * dinv[n] + b3[c];
    h3[t] = v > 0.f ? v : 0.f;
}

// ---------------- head: z[b][j] = h3[b,:] . Wl1[:,j] + bl1[j] ----------------

__global__ void k_head(const float* __restrict__ h3, const float* __restrict__ Wl1,
                       const float* __restrict__ bl1, float* __restrict__ z) {
    int b = blockIdx.x >> 5;
    int j = blockIdx.x & 31;
    int lane = threadIdx.x;  // blockDim = 64
    float acc = 0.f;
    for (int k = lane; k < HEADK; k += 64)
        acc += h3[b * HEADK + k] * Wl1[k * 32 + j];
#pragma unroll
    for (int off = 32; off; off >>= 1) acc += __shfl_down(acc, off);
    if (lane == 0) z[b * 32 + j] = acc + bl1[j];
}

// ---------------- BN (biased var) + ReLU + final linear ----------------

__global__ void k_bn_final(const float* __restrict__ z, const float* __restrict__ gamma,
                           const float* __restrict__ beta, const float* __restrict__ Wl2,
                           const float* __restrict__ bl2, float* __restrict__ out) {
    __shared__ float zs[NB][32];
    __shared__ float scale[32], shift[32];
    int tid = threadIdx.x;  // 256
    for (int i = tid; i < NB * 32; i += 256) zs[i >> 5][i & 31] = z[i];
    __syncthreads();
    if (tid < 32) {
        float m = 0.f, v = 0.f;
        for (int b = 0; b < NB; ++b) { float xv = zs[b][tid]; m += xv; v += xv * xv; }
        m /= (float)NB;
        v = v / (float)NB - m * m;
        float sc = gamma[tid] * rsqrtf(v + BN_EPS);
        scale[tid] = sc;
        shift[tid] = beta[tid] - m * sc;
    }
    __syncthreads();
    if (tid < NB) {
        float acc = bl2[0];
#pragma unroll
        for (int j = 0; j < 32; ++j) {
            float zv = zs[tid][j] * scale[j] + shift[j];
            zv = zv > 0.f ? zv : 0.f;
            acc += zv * Wl2[j];
        }
        out[tid] = acc;
    }
}

// ---------------- launch ----------------

extern "C" void kernel_launch(void* const* d_in, const int* in_sizes, int n_in,
                              void* d_out, int out_size, void* d_ws, size_t ws_size,
                              hipStream_t stream) {
    const float* x    = (const float*)d_in[0];
    const int*   ei   = (const int*)d_in[1];
    const float* W1   = (const float*)d_in[2];
    const float* b1   = (const float*)d_in[3];
    const float* W2   = (const float*)d_in[4];
    const float* b2   = (const float*)d_in[5];
    const float* W3   = (const float*)d_in[6];
    const float* b3   = (const float*)d_in[7];
    const float* Wl1  = (const float*)d_in[8];
    const float* bl1  = (const float*)d_in[9];
    const float* gamma= (const float*)d_in[10];
    const float* beta = (const float*)d_in[11];
    const float* Wl2  = (const float*)d_in[12];
    const float* bl2  = (const float*)d_in[13];

    const int* src = ei;            // edge_index[0]
    const int* dst = ei + NEDGES;   // edge_index[1]

    char* ws = (char*)d_ws;
    size_t off = 0;
    float* dinv = (float*)(ws + off); off += (size_t)NNODES * 4;
    int*   deg  = (int*)  (ws + off); off += (size_t)NNODES * 4;
    float* xs   = (float*)(ws + off); off += (size_t)NNODES * 5 * 4;
    float* agg1 = (float*)(ws + off); off += (size_t)NNODES * 5 * 4;
    float* g2s  = (float*)(ws + off); off += (size_t)NNODES * 16 * 4;
    float* agg2 = (float*)(ws + off); off += (size_t)NNODES * 16 * 4;
    float* g3s  = (float*)(ws + off); off += (size_t)NNODES * 3 * 4;
    float* agg3 = (float*)(ws + off); off += (size_t)NNODES * 3 * 4;
    float* h3   = (float*)(ws + off); off += (size_t)NNODES * 3 * 4;
    float* z    = (float*)(ws + off); off += (size_t)NB * 32 * 4;

    float* outp = (float*)d_out;

    // degrees + dinv (graph identical for all 3 layers)
    hipMemsetAsync(deg, 0, (size_t)NNODES * 4, stream);
    k_deg<<<(NEDGES + 255) / 256, 256, 0, stream>>>(dst, deg);
    k_dinv<<<(NNODES + 255) / 256, 256, 0, stream>>>(deg, dinv);

    // ---- layer 1 aggregation in 5-dim input space
    k_pre1<<<(int)(((unsigned)NNODES * 5u + 255) / 256), 256, 0, stream>>>(x, dinv, xs, agg1);
    k_scatter5<<<(int)(((unsigned)NEDGES * 5u + 255) / 256), 256, 0, stream>>>(src, dst, xs, agg1);

    // ---- fused mm1 + relu + mm2 + prescale (writes g2s + agg2 self-init)
    k_mm12<<<(NNODES + 255) / 256, 256, 0, stream>>>(agg1, dinv, W1, b1, W2, g2s, agg2);
    k_scatter16<<<(int)(((unsigned)NEDGES * 16u + 255) / 256), 256, 0, stream>>>(src, dst, g2s, agg2);

    // ---- fused relu(layer2) + mm3 + prescale (writes g3s + agg3 self-init)
    k_mm3<<<(NNODES + 255) / 256, 256, 0, stream>>>(agg2, dinv, b2, W3, g3s, agg3);
    k_scatter3<<<(int)(((unsigned)NEDGES * 3u + 255) / 256), 256, 0, stream>>>(src, dst, g3s, agg3);

    // ---- finalize h3, head, BN + final linear
    k_final3<<<(int)(((unsigned)NNODES * 3u + 255) / 256), 256, 0, stream>>>(agg3, dinv, b3, h3);
    k_head<<<NB * 32, 64, 0, stream>>>(h3, Wl1, bl1, z);
    k_bn_final<<<1, 256, 0, stream>>>(z, gamma, beta, Wl2, bl2, outp);
}

// Round 3
// 505.138 us; speedup vs baseline: 1.8330x; 1.1561x over previous
//
#include <hip/hip_runtime.h>

#define NNODES 149120
#define NEDGES 2385920
#define NB 64
#define NPMTS 2330
#define HEADK (NPMTS * 3)   // 6990
#define BN_EPS 1e-5f
#define NBLK ((NNODES + 255) / 256)   // 583

// ---------------- degree ----------------

__global__ void k_deg(const int* __restrict__ dst, int* __restrict__ deg) {
    int i = blockIdx.x * blockDim.x + threadIdx.x;
    if (i < NEDGES) atomicAdd(&deg[dst[i]], 1);
}

// ---------------- CSR build: block sums -> scan -> row_start -> fill ----------------

__global__ void k_blockred(const int* __restrict__ deg, int* __restrict__ bsum) {
    __shared__ int s[256];
    int t = threadIdx.x;
    int n = blockIdx.x * 256 + t;
    s[t] = (n < NNODES) ? deg[n] : 0;
    __syncthreads();
    for (int o = 128; o; o >>= 1) {
        if (t < o) s[t] += s[t + o];
        __syncthreads();
    }
    if (t == 0) bsum[blockIdx.x] = s[0];
}

__global__ void k_bscan(const int* __restrict__ bsum, int* __restrict__ boff) {
    __shared__ int s[1024];
    int t = threadIdx.x;
    s[t] = (t < NBLK) ? bsum[t] : 0;
    __syncthreads();
    for (int o = 1; o < 1024; o <<= 1) {
        int v = (t >= o) ? s[t - o] : 0;
        __syncthreads();
        s[t] += v;
        __syncthreads();
    }
    if (t < NBLK) boff[t] = t ? s[t - 1] : 0;
}

__global__ void k_rowstart(const int* __restrict__ deg, const int* __restrict__ boff,
                           int* __restrict__ rowstart, int* __restrict__ cursor,
                           float* __restrict__ dinv) {
    __shared__ int s[256];
    int t = threadIdx.x;
    int n = blockIdx.x * 256 + t;
    int d = (n < NNODES) ? deg[n] : 0;
    s[t] = d;
    __syncthreads();
    for (int o = 1; o < 256; o <<= 1) {   // inclusive scan
        int v = (t >= o) ? s[t - o] : 0;
        __syncthreads();
        s[t] += v;
        __syncthreads();
    }
    if (n < NNODES) {
        int rs = boff[blockIdx.x] + s[t] - d;   // exclusive
        rowstart[n] = rs;
        cursor[n] = rs;
        dinv[n] = rsqrtf((float)(d + 1));       // +1 self-loop
    }
}

__global__ void k_fill(const int* __restrict__ src, const int* __restrict__ dst,
                       int* __restrict__ cursor, int* __restrict__ csr) {
    int e = blockIdx.x * blockDim.x + threadIdx.x;
    if (e < NEDGES) {
        int pos = atomicAdd(&cursor[dst[e]], 1);
        csr[pos] = src[e];
    }
}

// ---------------- layer-1 pre-scale into padded rows: xs8[n][8] = x[n][0..4]*dinv ----------------

__global__ void k_pre1(const float* __restrict__ x, const float* __restrict__ dinv,
                       float* __restrict__ xs8) {
    unsigned t = blockIdx.x * blockDim.x + threadIdx.x;
    if (t >= (unsigned)NNODES * 8u) return;
    unsigned n = t >> 3, c = t & 7u;
    xs8[t] = (c < 5u) ? x[n * 5u + c] * dinv[n] : 0.f;
}

// ---------------- gathers: agg[n] = buf[n] (self) + sum_{s in in(n)} buf[s] ----------------

__global__ void k_gather8(const int* __restrict__ rowstart, const int* __restrict__ deg,
                          const int* __restrict__ csr, const float* __restrict__ xs8,
                          float* __restrict__ agg8) {
    unsigned t = blockIdx.x * blockDim.x + threadIdx.x;
    unsigned g = t >> 3, c = t & 7u;
    if (g >= NNODES) return;
    int rs = rowstart[g], d = deg[g];
    float acc = xs8[g * 8u + c];
    for (int j = 0; j < d; ++j) {
        int s = csr[rs + j];
        acc += xs8[(unsigned)s * 8u + c];
    }
    agg8[g * 8u + c] = acc;
}

__global__ void k_gather16(const int* __restrict__ rowstart, const int* __restrict__ deg,
                           const int* __restrict__ csr, const float* __restrict__ g2s,
                           float* __restrict__ agg2) {
    unsigned t = blockIdx.x * blockDim.x + threadIdx.x;
    unsigned g = t >> 4, c = t & 15u;
    if (g >= NNODES) return;
    int rs = rowstart[g], d = deg[g];
    float acc = g2s[g * 16u + c];
    for (int j = 0; j < d; ++j) {
        int s = csr[rs + j];
        acc += g2s[(unsigned)s * 16u + c];
    }
    agg2[g * 16u + c] = acc;
}

__global__ void k_gather4_final(const int* __restrict__ rowstart, const int* __restrict__ deg,
                                const int* __restrict__ csr, const float* __restrict__ g3s4,
                                const float* __restrict__ dinv, const float* __restrict__ b3,
                                float* __restrict__ h3) {
    unsigned t = blockIdx.x * blockDim.x + threadIdx.x;
    unsigned g = t >> 2, c = t & 3u;
    if (g >= NNODES) return;
    int rs = rowstart[g], d = deg[g];
    float acc = g3s4[g * 4u + c];
    for (int j = 0; j < d; ++j) {
        int s = csr[rs + j];
        acc += g3s4[(unsigned)s * 4u + c];
    }
    if (c < 3u) {
        float v = acc * dinv[g] + b3[c];
        h3[g * 3u + c] = v > 0.f ? v : 0.f;
    }
}

// ---------------- fused: h1 = relu(agg8*dinv @ W1 + b1); g2s = (h1@W2)*dinv ----------------

__global__ void k_mm12(const float* __restrict__ agg8, const float* __restrict__ dinv,
                       const float* __restrict__ W1, const float* __restrict__ b1,
                       const float* __restrict__ W2, float* __restrict__ g2s) {
    __shared__ float W1s[5 * 32], W2s[32 * 16], b1s[32];
    int tid = threadIdx.x;  // 256
    if (tid < 5 * 32) W1s[tid] = W1[tid];
    if (tid < 32) b1s[tid] = b1[tid];
    for (int i = tid; i < 32 * 16; i += 256) W2s[i] = W2[i];
    __syncthreads();

    unsigned n = blockIdx.x * blockDim.x + tid;
    if (n >= NNODES) return;
    float di = dinv[n];
    float a[5];
#pragma unroll
    for (int k = 0; k < 5; ++k) a[k] = agg8[n * 8u + k] * di;

    float h[32];
#pragma unroll
    for (int j = 0; j < 32; ++j) {
        float acc = b1s[j];
#pragma unroll
        for (int k = 0; k < 5; ++k) acc += a[k] * W1s[k * 32 + j];
        h[j] = acc > 0.f ? acc : 0.f;
    }
    float g[16];
#pragma unroll
    for (int c = 0; c < 16; ++c) g[c] = 0.f;
#pragma unroll
    for (int j = 0; j < 32; ++j) {
        float hj = h[j];
#pragma unroll
        for (int c = 0; c < 16; ++c) g[c] += hj * W2s[j * 16 + c];
    }
#pragma unroll
    for (int c = 0; c < 16; ++c) g2s[n * 16u + c] = g[c] * di;
}

// ---------------- fused: t2 = relu(agg2*dinv + b2); g3s4 = (t2@W3)*dinv (pad slot=0) ----------------

__global__ void k_mm3(const float* __restrict__ agg2, const float* __restrict__ dinv,
                      const float* __restrict__ b2, const float* __restrict__ W3,
                      float* __restrict__ g3s4) {
    __shared__ float W3s[16 * 3], b2s[16];
    int tid = threadIdx.x;
    if (tid < 16 * 3) W3s[tid] = W3[tid];
    if (tid < 16) b2s[tid] = b2[tid];
    __syncthreads();

    unsigned n = blockIdx.x * blockDim.x + tid;
    if (n >= NNODES) return;
    float di = dinv[n];
    float t2[16];
#pragma unroll
    for (int j = 0; j < 16; ++j) {
        float v = agg2[n * 16u + j] * di + b2s[j];
        t2[j] = v > 0.f ? v : 0.f;
    }
    float g[3] = {0.f, 0.f, 0.f};
#pragma unroll
    for (int j = 0; j < 16; ++j) {
        float tj = t2[j];
#pragma unroll
        for (int c = 0; c < 3; ++c) g[c] += tj * W3s[j * 3 + c];
    }
#pragma unroll
    for (int c = 0; c < 3; ++c) g3s4[n * 4u + c] = g[c] * di;
    g3s4[n * 4u + 3] = 0.f;
}

// ---------------- head: z[b][j] = h3[b,:] . Wl1[:,j] + bl1[j] ----------------

__global__ void k_head(const float* __restrict__ h3, const float* __restrict__ Wl1,
                       const float* __restrict__ bl1, float* __restrict__ z) {
    int b = blockIdx.x >> 5;
    int j = blockIdx.x & 31;
    int lane = threadIdx.x;  // blockDim = 64
    float acc = 0.f;
    for (int k = lane; k < HEADK; k += 64)
        acc += h3[b * HEADK + k] * Wl1[k * 32 + j];
#pragma unroll
    for (int off = 32; off; off >>= 1) acc += __shfl_down(acc, off);
    if (lane == 0) z[b * 32 + j] = acc + bl1[j];
}

// ---------------- BN (biased var) + ReLU + final linear ----------------

__global__ void k_bn_final(const float* __restrict__ z, const float* __restrict__ gamma,
                           const float* __restrict__ beta, const float* __restrict__ Wl2,
                           const float* __restrict__ bl2, float* __restrict__ out) {
    __shared__ float zs[NB][32];
    __shared__ float scale[32], shift[32];
    int tid = threadIdx.x;  // 256
    for (int i = tid; i < NB * 32; i += 256) zs[i >> 5][i & 31] = z[i];
    __syncthreads();
    if (tid < 32) {
        float m = 0.f, v = 0.f;
        for (int b = 0; b < NB; ++b) { float xv = zs[b][tid]; m += xv; v += xv * xv; }
        m /= (float)NB;
        v = v / (float)NB - m * m;
        float sc = gamma[tid] * rsqrtf(v + BN_EPS);
        scale[tid] = sc;
        shift[tid] = beta[tid] - m * sc;
    }
    __syncthreads();
    if (tid < NB) {
        float acc = bl2[0];
#pragma unroll
        for (int j = 0; j < 32; ++j) {
            float zv = zs[tid][j] * scale[j] + shift[j];
            zv = zv > 0.f ? zv : 0.f;
            acc += zv * Wl2[j];
        }
        out[tid] = acc;
    }
}

// ---------------- launch ----------------

extern "C" void kernel_launch(void* const* d_in, const int* in_sizes, int n_in,
                              void* d_out, int out_size, void* d_ws, size_t ws_size,
                              hipStream_t stream) {
    const float* x    = (const float*)d_in[0];
    const int*   ei   = (const int*)d_in[1];
    const float* W1   = (const float*)d_in[2];
    const float* b1   = (const float*)d_in[3];
    const float* W2   = (const float*)d_in[4];
    const float* b2   = (const float*)d_in[5];
    const float* W3   = (const float*)d_in[6];
    const float* b3   = (const float*)d_in[7];
    const float* Wl1  = (const float*)d_in[8];
    const float* bl1  = (const float*)d_in[9];
    const float* gamma= (const float*)d_in[10];
    const float* beta = (const float*)d_in[11];
    const float* Wl2  = (const float*)d_in[12];
    const float* bl2  = (const float*)d_in[13];

    const int* src = ei;            // edge_index[0]
    const int* dst = ei + NEDGES;   // edge_index[1]

    char* ws = (char*)d_ws;
    size_t off = 0;
    float* dinv     = (float*)(ws + off); off += (size_t)NNODES * 4;
    int*   deg      = (int*)  (ws + off); off += (size_t)NNODES * 4;
    int*   bsum     = (int*)  (ws + off); off += (size_t)1024 * 4;
    int*   boff     = (int*)  (ws + off); off += (size_t)1024 * 4;
    int*   rowstart = (int*)  (ws + off); off += (size_t)NNODES * 4;
    int*   cursor   = (int*)  (ws + off); off += (size_t)NNODES * 4;
    int*   csr      = (int*)  (ws + off); off += (size_t)NEDGES * 4;
    float* xs8      = (float*)(ws + off); off += (size_t)NNODES * 8 * 4;
    float* agg8     = (float*)(ws + off); off += (size_t)NNODES * 8 * 4;
    float* g2s      = (float*)(ws + off); off += (size_t)NNODES * 16 * 4;
    float* agg2     = (float*)(ws + off); off += (size_t)NNODES * 16 * 4;
    float* g3s4     = (float*)(ws + off); off += (size_t)NNODES * 4 * 4;
    float* h3       = (float*)(ws + off); off += (size_t)NNODES * 3 * 4;
    float* z        = (float*)(ws + off); off += (size_t)NB * 32 * 4;

    float* outp = (float*)d_out;

    // ---- degree + CSR build (graph identical for all 3 layers)
    hipMemsetAsync(deg, 0, (size_t)NNODES * 4, stream);
    k_deg<<<(NEDGES + 255) / 256, 256, 0, stream>>>(dst, deg);
    k_blockred<<<NBLK, 256, 0, stream>>>(deg, bsum);
    k_bscan<<<1, 1024, 0, stream>>>(bsum, boff);
    k_rowstart<<<NBLK, 256, 0, stream>>>(deg, boff, rowstart, cursor, dinv);
    k_fill<<<(NEDGES + 255) / 256, 256, 0, stream>>>(src, dst, cursor, csr);

    // ---- layer 1: aggregate in 5-dim (padded 8) input space, gather-based
    k_pre1<<<(int)(((unsigned)NNODES * 8u + 255) / 256), 256, 0, stream>>>(x, dinv, xs8);
    k_gather8<<<(int)(((unsigned)NNODES * 8u + 255) / 256), 256, 0, stream>>>(
        rowstart, deg, csr, xs8, agg8);

    // ---- fused mm1 + relu + mm2 + prescale
    k_mm12<<<(NNODES + 255) / 256, 256, 0, stream>>>(agg8, dinv, W1, b1, W2, g2s);
    k_gather16<<<(int)(((unsigned)NNODES * 16u + 255) / 256), 256, 0, stream>>>(
        rowstart, deg, csr, g2s, agg2);

    // ---- fused relu(layer2) + mm3 + prescale
    k_mm3<<<(NNODES + 255) / 256, 256, 0, stream>>>(agg2, dinv, b2, W3, g3s4);
    k_gather4_final<<<(int)(((unsigned)NNODES * 4u + 255) / 256), 256, 0, stream>>>(
        rowstart, deg, csr, g3s4, dinv, b3, h3);

    // ---- head + BN + final linear
    k_head<<<NB * 32, 64, 0, stream>>>(h3, Wl1, bl1, z);
    k_bn_final<<<1, 256, 0, stream>>>(z, gamma, beta, Wl2, bl2, outp);
}

// Round 4
// 383.995 us; speedup vs baseline: 2.4113x; 1.3155x over previous
//
#include <hip/hip_runtime.h>

#define NNODES 149120
#define NEDGES 2385920
#define NB 64
#define NPMTS 2330
#define HEADK (NPMTS * 3)   // 6990
#define BN_EPS 1e-5f
#define NBLK ((NNODES + 255) / 256)   // 583

#define FILL_K 8
#define BUCKET_N (NNODES / FILL_K)    // 18640
#define FILL_CHUNKS 256
#define FILL_PER (NEDGES / FILL_CHUNKS)  // 9320

#define HEAD_SEG 4
#define SEGK ((HEADK + HEAD_SEG - 1) / HEAD_SEG)   // 1748

// ---------------- degree ----------------

__global__ void k_deg(const int* __restrict__ dst, int* __restrict__ deg) {
    int i = blockIdx.x * blockDim.x + threadIdx.x;
    if (i < NEDGES) atomicAdd(&deg[dst[i]], 1);
}

// ---------------- CSR build: block sums -> scan -> row_start -> bucketed fill ----------------

__global__ void k_blockred(const int* __restrict__ deg, int* __restrict__ bsum) {
    __shared__ int s[256];
    int t = threadIdx.x;
    int n = blockIdx.x * 256 + t;
    s[t] = (n < NNODES) ? deg[n] : 0;
    __syncthreads();
    for (int o = 128; o; o >>= 1) {
        if (t < o) s[t] += s[t + o];
        __syncthreads();
    }
    if (t == 0) bsum[blockIdx.x] = s[0];
}

__global__ void k_bscan(const int* __restrict__ bsum, int* __restrict__ boff) {
    __shared__ int s[1024];
    int t = threadIdx.x;
    s[t] = (t < NBLK) ? bsum[t] : 0;
    __syncthreads();
    for (int o = 1; o < 1024; o <<= 1) {
        int v = (t >= o) ? s[t - o] : 0;
        __syncthreads();
        s[t] += v;
        __syncthreads();
    }
    if (t < NBLK) boff[t] = t ? s[t - 1] : 0;
}

__global__ void k_rowstart(const int* __restrict__ deg, const int* __restrict__ boff,
                           int* __restrict__ rowstart, int* __restrict__ cursor,
                           float* __restrict__ dinv) {
    __shared__ int s[256];
    int t = threadIdx.x;
    int n = blockIdx.x * 256 + t;
    int d = (n < NNODES) ? deg[n] : 0;
    s[t] = d;
    __syncthreads();
    for (int o = 1; o < 256; o <<= 1) {   // inclusive scan
        int v = (t >= o) ? s[t - o] : 0;
        __syncthreads();
        s[t] += v;
        __syncthreads();
    }
    if (n < NNODES) {
        int rs = boff[blockIdx.x] + s[t] - d;   // exclusive
        rowstart[n] = rs;
        cursor[n] = rs;
        dinv[n] = rsqrtf((float)(d + 1));       // +1 self-loop
    }
}

// Bucketed fill: block (chunk, bucket); bucket = blockIdx&7 -> round-robin XCD,
// so each bucket's 1.2MB csr region stays resident in one XCD's L2 and each
// 64B line evicts once instead of ~16 times. Edge stream read via NT loads.
__global__ void k_fill_bucket(const int* __restrict__ src, const int* __restrict__ dst,
                              int* __restrict__ cursor, int* __restrict__ csr) {
    int bucket = blockIdx.x & (FILL_K - 1);
    int chunk  = blockIdx.x >> 3;
    int lo = bucket * BUCKET_N, hi = lo + BUCKET_N;
    int e0 = chunk * FILL_PER;
    int e1 = e0 + FILL_PER;
    if (e1 > NEDGES) e1 = NEDGES;
    for (int e = e0 + threadIdx.x; e < e1; e += 256) {
        int d = __builtin_nontemporal_load(&dst[e]);
        if (d >= lo && d < hi) {
            int s = __builtin_nontemporal_load(&src[e]);
            int pos = atomicAdd(&cursor[d], 1);
            csr[pos] = s;
        }
    }
}

// ---------------- layer-1 pre-scale into padded rows: xs8[n][8] = x[n][0..4]*dinv ----------------

__global__ void k_pre1(const float* __restrict__ x, const float* __restrict__ dinv,
                       float* __restrict__ xs8) {
    unsigned t = blockIdx.x * blockDim.x + threadIdx.x;
    if (t >= (unsigned)NNODES * 8u) return;
    unsigned n = t >> 3, c = t & 7u;
    xs8[t] = (c < 5u) ? x[n * 5u + c] * dinv[n] : 0.f;
}

// ---------------- gathers (float4, unroll-4): agg[n] = buf[n] + sum_{s in in(n)} buf[s] ----------------

__global__ void k_gather8v(const int* __restrict__ rowstart, const int* __restrict__ deg,
                           const int* __restrict__ csr, const float4* __restrict__ xs,
                           float4* __restrict__ agg) {
    unsigned t = blockIdx.x * blockDim.x + threadIdx.x;
    unsigned g = t >> 1, c = t & 1u;
    if (g >= NNODES) return;
    int rs = rowstart[g], d = deg[g];
    float4 acc = xs[g * 2u + c];
    int j = 0;
    for (; j + 4 <= d; j += 4) {
        int s0 = csr[rs + j], s1 = csr[rs + j + 1], s2 = csr[rs + j + 2], s3 = csr[rs + j + 3];
        float4 v0 = xs[(unsigned)s0 * 2u + c], v1 = xs[(unsigned)s1 * 2u + c];
        float4 v2 = xs[(unsigned)s2 * 2u + c], v3 = xs[(unsigned)s3 * 2u + c];
        acc.x += v0.x + v1.x + v2.x + v3.x;
        acc.y += v0.y + v1.y + v2.y + v3.y;
        acc.z += v0.z + v1.z + v2.z + v3.z;
        acc.w += v0.w + v1.w + v2.w + v3.w;
    }
    for (; j < d; ++j) {
        float4 v = xs[(unsigned)csr[rs + j] * 2u + c];
        acc.x += v.x; acc.y += v.y; acc.z += v.z; acc.w += v.w;
    }
    agg[g * 2u + c] = acc;
}

__global__ void k_gather16v(const int* __restrict__ rowstart, const int* __restrict__ deg,
                            const int* __restrict__ csr, const float4* __restrict__ gs,
                            float4* __restrict__ agg) {
    unsigned t = blockIdx.x * blockDim.x + threadIdx.x;
    unsigned g = t >> 2, c = t & 3u;
    if (g >= NNODES) return;
    int rs = rowstart[g], d = deg[g];
    float4 acc = gs[g * 4u + c];
    int j = 0;
    for (; j + 4 <= d; j += 4) {
        int s0 = csr[rs + j], s1 = csr[rs + j + 1], s2 = csr[rs + j + 2], s3 = csr[rs + j + 3];
        float4 v0 = gs[(unsigned)s0 * 4u + c], v1 = gs[(unsigned)s1 * 4u + c];
        float4 v2 = gs[(unsigned)s2 * 4u + c], v3 = gs[(unsigned)s3 * 4u + c];
        acc.x += v0.x + v1.x + v2.x + v3.x;
        acc.y += v0.y + v1.y + v2.y + v3.y;
        acc.z += v0.z + v1.z + v2.z + v3.z;
        acc.w += v0.w + v1.w + v2.w + v3.w;
    }
    for (; j < d; ++j) {
        float4 v = gs[(unsigned)csr[rs + j] * 4u + c];
        acc.x += v.x; acc.y += v.y; acc.z += v.z; acc.w += v.w;
    }
    agg[g * 4u + c] = acc;
}

__global__ void k_gather4_final(const int* __restrict__ rowstart, const int* __restrict__ deg,
                                const int* __restrict__ csr, const float4* __restrict__ g3,
                                const float* __restrict__ dinv, const float* __restrict__ b3,
                                float* __restrict__ h3) {
    unsigned g = blockIdx.x * blockDim.x + threadIdx.x;
    if (g >= NNODES) return;
    int rs = rowstart[g], d = deg[g];
    float4 acc = g3[g];
    int j = 0;
    for (; j + 4 <= d; j += 4) {
        int s0 = csr[rs + j], s1 = csr[rs + j + 1], s2 = csr[rs + j + 2], s3 = csr[rs + j + 3];
        float4 v0 = g3[s0], v1 = g3[s1], v2 = g3[s2], v3 = g3[s3];
        acc.x += v0.x + v1.x + v2.x + v3.x;
        acc.y += v0.y + v1.y + v2.y + v3.y;
        acc.z += v0.z + v1.z + v2.z + v3.z;
    }
    for (; j < d; ++j) {
        float4 v = g3[csr[rs + j]];
        acc.x += v.x; acc.y += v.y; acc.z += v.z;
    }
    float di = dinv[g];
    float o0 = acc.x * di + b3[0];
    float o1 = acc.y * di + b3[1];
    float o2 = acc.z * di + b3[2];
    h3[g * 3u + 0] = o0 > 0.f ? o0 : 0.f;
    h3[g * 3u + 1] = o1 > 0.f ? o1 : 0.f;
    h3[g * 3u + 2] = o2 > 0.f ? o2 : 0.f;
}

// ---------------- fused: h1 = relu(agg8*dinv @ W1 + b1); g2s = (h1@W2)*dinv ----------------

__global__ void k_mm12(const float* __restrict__ agg8, const float* __restrict__ dinv,
                       const float* __restrict__ W1, const float* __restrict__ b1,
                       const float* __restrict__ W2, float* __restrict__ g2s) {
    __shared__ float W1s[5 * 32], W2s[32 * 16], b1s[32];
    int tid = threadIdx.x;  // 256
    if (tid < 5 * 32) W1s[tid] = W1[tid];
    if (tid < 32) b1s[tid] = b1[tid];
    for (int i = tid; i < 32 * 16; i += 256) W2s[i] = W2[i];
    __syncthreads();

    unsigned n = blockIdx.x * blockDim.x + tid;
    if (n >= NNODES) return;
    float di = dinv[n];
    float a[5];
#pragma unroll
    for (int k = 0; k < 5; ++k) a[k] = agg8[n * 8u + k] * di;

    float h[32];
#pragma unroll
    for (int j = 0; j < 32; ++j) {
        float acc = b1s[j];
#pragma unroll
        for (int k = 0; k < 5; ++k) acc += a[k] * W1s[k * 32 + j];
        h[j] = acc > 0.f ? acc : 0.f;
    }
    float g[16];
#pragma unroll
    for (int c = 0; c < 16; ++c) g[c] = 0.f;
#pragma unroll
    for (int j = 0; j < 32; ++j) {
        float hj = h[j];
#pragma unroll
        for (int c = 0; c < 16; ++c) g[c] += hj * W2s[j * 16 + c];
    }
#pragma unroll
    for (int c = 0; c < 16; ++c) g2s[n * 16u + c] = g[c] * di;
}

// ---------------- fused: t2 = relu(agg2*dinv + b2); g3s4 = (t2@W3)*dinv (pad slot=0) ----------------

__global__ void k_mm3(const float* __restrict__ agg2, const float* __restrict__ dinv,
                      const float* __restrict__ b2, const float* __restrict__ W3,
                      float* __restrict__ g3s4) {
    __shared__ float W3s[16 * 3], b2s[16];
    int tid = threadIdx.x;
    if (tid < 16 * 3) W3s[tid] = W3[tid];
    if (tid < 16) b2s[tid] = b2[tid];
    __syncthreads();

    unsigned n = blockIdx.x * blockDim.x + tid;
    if (n >= NNODES) return;
    float di = dinv[n];
    float t2[16];
#pragma unroll
    for (int j = 0; j < 16; ++j) {
        float v = agg2[n * 16u + j] * di + b2s[j];
        t2[j] = v > 0.f ? v : 0.f;
    }
    float g[3] = {0.f, 0.f, 0.f};
#pragma unroll
    for (int j = 0; j < 16; ++j) {
        float tj = t2[j];
#pragma unroll
        for (int c = 0; c < 3; ++c) g[c] += tj * W3s[j * 3 + c];
    }
#pragma unroll
    for (int c = 0; c < 3; ++c) g3s4[n * 4u + c] = g[c] * di;
    g3s4[n * 4u + 3] = 0.f;
}

// ---------------- head: zpart[seg][b][j] = sum_{k in seg} h3[b,k] * Wl1[k,j] ----------------

__global__ void k_head2(const float* __restrict__ h3, const float* __restrict__ Wl1,
                        float* __restrict__ zpart) {
    __shared__ float hrow[SEGK];
    __shared__ float part[8][32];
    int b = blockIdx.x >> 2, seg = blockIdx.x & 3;
    int k0 = seg * SEGK;
    int kend = k0 + SEGK; if (kend > HEADK) kend = HEADK;
    int cnt = kend - k0;
    for (int k = threadIdx.x; k < cnt; k += 256) hrow[k] = h3[b * HEADK + k0 + k];
    __syncthreads();
    int j = threadIdx.x & 31, g = threadIdx.x >> 5;
    float acc = 0.f;
    for (int k = g; k < cnt; k += 8) acc += hrow[k] * Wl1[(k0 + k) * 32 + j];
    part[g][j] = acc;
    __syncthreads();
    if (threadIdx.x < 32) {
        float s = 0.f;
#pragma unroll
        for (int g2 = 0; g2 < 8; ++g2) s += part[g2][j];
        zpart[(seg * NB + b) * 32 + j] = s;
    }
}

// ---------------- BN (biased var) + ReLU + final linear ----------------

__global__ void k_bn_final(const float* __restrict__ zpart, const float* __restrict__ bl1,
                           const float* __restrict__ gamma, const float* __restrict__ beta,
                           const float* __restrict__ Wl2, const float* __restrict__ bl2,
                           float* __restrict__ out) {
    __shared__ float zs[NB][32];
    __shared__ float scale[32], shift[32];
    int tid = threadIdx.x;  // 256
    for (int i = tid; i < NB * 32; i += 256) {
        float v = bl1[i & 31];
#pragma unroll
        for (int sgm = 0; sgm < 4; ++sgm) v += zpart[sgm * NB * 32 + i];
        zs[i >> 5][i & 31] = v;
    }
    __syncthreads();
    if (tid < 32) {
        float m = 0.f, v = 0.f;
        for (int b = 0; b < NB; ++b) { float xv = zs[b][tid]; m += xv; v += xv * xv; }
        m /= (float)NB;
        v = v / (float)NB - m * m;
        float sc = gamma[tid] * rsqrtf(v + BN_EPS);
        scale[tid] = sc;
        shift[tid] = beta[tid] - m * sc;
    }
    __syncthreads();
    if (tid < NB) {
        float acc = bl2[0];
#pragma unroll
        for (int j = 0; j < 32; ++j) {
            float zv = zs[tid][j] * scale[j] + shift[j];
            zv = zv > 0.f ? zv : 0.f;
            acc += zv * Wl2[j];
        }
        out[tid] = acc;
    }
}

// ---------------- launch ----------------

extern "C" void kernel_launch(void* const* d_in, const int* in_sizes, int n_in,
                              void* d_out, int out_size, void* d_ws, size_t ws_size,
                              hipStream_t stream) {
    const float* x    = (const float*)d_in[0];
    const int*   ei   = (const int*)d_in[1];
    const float* W1   = (const float*)d_in[2];
    const float* b1   = (const float*)d_in[3];
    const float* W2   = (const float*)d_in[4];
    const float* b2   = (const float*)d_in[5];
    const float* W3   = (const float*)d_in[6];
    const float* b3   = (const float*)d_in[7];
    const float* Wl1  = (const float*)d_in[8];
    const float* bl1  = (const float*)d_in[9];
    const float* gamma= (const float*)d_in[10];
    const float* beta = (const float*)d_in[11];
    const float* Wl2  = (const float*)d_in[12];
    const float* bl2  = (const float*)d_in[13];

    const int* src = ei;            // edge_index[0]
    const int* dst = ei + NEDGES;   // edge_index[1]

    char* ws = (char*)d_ws;
    size_t off = 0;
    float* dinv     = (float*)(ws + off); off += (size_t)NNODES * 4;
    int*   deg      = (int*)  (ws + off); off += (size_t)NNODES * 4;
    int*   bsum     = (int*)  (ws + off); off += (size_t)1024 * 4;
    int*   boff     = (int*)  (ws + off); off += (size_t)1024 * 4;
    int*   rowstart = (int*)  (ws + off); off += (size_t)NNODES * 4;
    int*   cursor   = (int*)  (ws + off); off += (size_t)NNODES * 4;
    int*   csr      = (int*)  (ws + off); off += (size_t)NEDGES * 4;
    float* xs8      = (float*)(ws + off); off += (size_t)NNODES * 8 * 4;
    float* agg8     = (float*)(ws + off); off += (size_t)NNODES * 8 * 4;
    float* g2s      = (float*)(ws + off); off += (size_t)NNODES * 16 * 4;
    float* agg2     = (float*)(ws + off); off += (size_t)NNODES * 16 * 4;
    float* g3s4     = (float*)(ws + off); off += (size_t)NNODES * 4 * 4;
    float* h3       = (float*)(ws + off); off += (size_t)NNODES * 3 * 4;
    float* zpart    = (float*)(ws + off); off += (size_t)4 * NB * 32 * 4;

    float* outp = (float*)d_out;

    // ---- degree + CSR build (graph identical for all 3 layers)
    hipMemsetAsync(deg, 0, (size_t)NNODES * 4, stream);
    k_deg<<<(NEDGES + 255) / 256, 256, 0, stream>>>(dst, deg);
    k_blockred<<<NBLK, 256, 0, stream>>>(deg, bsum);
    k_bscan<<<1, 1024, 0, stream>>>(bsum, boff);
    k_rowstart<<<NBLK, 256, 0, stream>>>(deg, boff, rowstart, cursor, dinv);
    k_fill_bucket<<<FILL_CHUNKS * FILL_K, 256, 0, stream>>>(src, dst, cursor, csr);

    // ---- layer 1: aggregate in 5-dim (padded 8) input space, gather-based
    k_pre1<<<(int)(((unsigned)NNODES * 8u + 255) / 256), 256, 0, stream>>>(x, dinv, xs8);
    k_gather8v<<<(int)(((unsigned)NNODES * 2u + 255) / 256), 256, 0, stream>>>(
        rowstart, deg, csr, (const float4*)xs8, (float4*)agg8);

    // ---- fused mm1 + relu + mm2 + prescale
    k_mm12<<<(NNODES + 255) / 256, 256, 0, stream>>>(agg8, dinv, W1, b1, W2, g2s);
    k_gather16v<<<(int)(((unsigned)NNODES * 4u + 255) / 256), 256, 0, stream>>>(
        rowstart, deg, csr, (const float4*)g2s, (float4*)agg2);

    // ---- fused relu(layer2) + mm3 + prescale
    k_mm3<<<(NNODES + 255) / 256, 256, 0, stream>>>(agg2, dinv, b2, W3, g3s4);
    k_gather4_final<<<(NNODES + 255) / 256, 256, 0, stream>>>(
        rowstart, deg, csr, (const float4*)g3s4, dinv, b3, h3);

    // ---- head + BN + final linear
    k_head2<<<NB * HEAD_SEG, 256, 0, stream>>>(h3, Wl1, zpart);
    k_bn_final<<<1, 256, 0, stream>>>(zpart, bl1, gamma, beta, Wl2, bl2, outp);
}